// Round 1
// baseline (139.588 us; speedup 1.0000x reference)
//
#include <hip/hip_runtime.h>
#include <hip/hip_bf16.h>

#define B_ 4
#define C_IN_ 384
#define C_OUT_ 768
#define N_ 8192
#define K_ 16
#define FANIN_ 192     // 2*C_IN/GROUPS
#define NT 32          // n-columns per block
#define PADC (2*C_IN_ + 8)   // 776: pad 8 bf16 to break 1536B-stride bank conflicts

typedef float f32x4 __attribute__((ext_vector_type(4)));
typedef short bf16x8 __attribute__((ext_vector_type(8)));

__device__ __forceinline__ unsigned short f2b(float f) {
  union { float f; unsigned u; } v; v.f = f;
  unsigned r = v.u + 0x7FFFu + ((v.u >> 16) & 1u);  // RNE
  return (unsigned short)(r >> 16);
}
__device__ __forceinline__ float b2f(unsigned short u) {
  union { unsigned u; float f; } v; v.u = ((unsigned)u) << 16; return v.f;
}

// ---- kernel 1: W fp32 -> bf16 ----
__global__ __launch_bounds__(256) void wconv_kernel(const float* __restrict__ W,
                                                    unsigned short* __restrict__ Wb) {
  int i = blockIdx.x * 256 + threadIdx.x;
  if (i < C_OUT_ * FANIN_) Wb[i] = f2b(W[i]);
}

// ---- kernel 2: transpose x [B][C][N] f32 -> xt [B][N][C] bf16 ----
__global__ __launch_bounds__(256) void transpose_kernel(const float* __restrict__ x,
                                                        unsigned short* __restrict__ xt) {
  __shared__ float tile[32][65];
  int n0 = blockIdx.x * 32;
  int c0 = blockIdx.y * 64;
  int b  = blockIdx.z;
  int tx = threadIdx.x & 31;   // n offset
  int ty = threadIdx.x >> 5;   // 0..7
  const float* xp = x + (size_t)b * C_IN_ * N_;
  #pragma unroll
  for (int r = 0; r < 8; ++r) {
    int c = c0 + r * 8 + ty;
    tile[tx][r * 8 + ty] = xp[(size_t)c * N_ + n0 + tx];   // coalesced along n
  }
  __syncthreads();
  unsigned short* outp = xt + ((size_t)b * N_ + n0) * C_IN_ + c0;
  int cp = threadIdx.x & 31;   // channel pair
  int ny = threadIdx.x >> 5;
  #pragma unroll
  for (int p = 0; p < 4; ++p) {
    int nl = ny + p * 8;
    unsigned pk = (unsigned)f2b(tile[nl][cp * 2]) |
                  ((unsigned)f2b(tile[nl][cp * 2 + 1]) << 16);
    *(unsigned*)(outp + (size_t)nl * C_IN_ + cp * 2) = pk;  // coalesced along c
  }
}

// ---- kernel 3: fused gather+max -> LDS merged tile -> grouped MFMA GEMM ----
__global__ __launch_bounds__(512) void mrconv_kernel(
    const unsigned short* __restrict__ xt,   // [B][N][C_IN] bf16
    const int* __restrict__ eidx,            // [2][B][N][K]
    const unsigned short* __restrict__ Wb,   // [C_OUT][FANIN] bf16
    const float* __restrict__ bias,          // [C_OUT]
    float* __restrict__ out)                 // [B][C_OUT][N]
{
  __shared__ unsigned short m_lds[NT][PADC];  // merged: interleaved (x_c, rel_c)
  int tile = blockIdx.x;
  int b    = blockIdx.y;
  int n0   = tile * NT;
  int tid  = threadIdx.x;
  int wv   = tid >> 6;
  int lane = tid & 63;

  const unsigned short* xtb = xt + (size_t)b * N_ * C_IN_;
  const int* e0p = eidx + ((size_t)b * N_) * K_;          // edge_index[0][b]
  const int* e1p = eidx + ((size_t)(B_ + b) * N_) * K_;   // edge_index[1][b]

  // -------- phase 1: gather + max-relative, write merged tile to LDS --------
  for (int s = 0; s < 4; ++s) {
    int nl = wv * 4 + s;                                   // 8 waves x 4 cols = 32
    int nb = __builtin_amdgcn_readfirstlane(n0 + nl);      // force SGPR -> s_loads
    const int* e0 = e0p + (size_t)nb * K_;
    const int* e1 = e1p + (size_t)nb * K_;
    if (lane < 48) {                                       // 48 lanes x 8ch = 384
      uint4 xv = *(const uint4*)(xtb + (size_t)nb * C_IN_ + lane * 8);
      unsigned ux[4] = {xv.x, xv.y, xv.z, xv.w};
      float rel[8];
      #pragma unroll
      for (int e = 0; e < 8; ++e) rel[e] = -1e30f;
      for (int k = 0; k < K_; ++k) {
        int j = e0[k];
        int i = e1[k];
        uint4 vj = *(const uint4*)(xtb + (size_t)j * C_IN_ + lane * 8);
        uint4 vi = *(const uint4*)(xtb + (size_t)i * C_IN_ + lane * 8);
        unsigned uj[4] = {vj.x, vj.y, vj.z, vj.w};
        unsigned ui[4] = {vi.x, vi.y, vi.z, vi.w};
        #pragma unroll
        for (int e = 0; e < 8; ++e) {
          float fj = b2f((unsigned short)((uj[e >> 1] >> ((e & 1) * 16)) & 0xffffu));
          float fi = b2f((unsigned short)((ui[e >> 1] >> ((e & 1) * 16)) & 0xffffu));
          rel[e] = fmaxf(rel[e], fj - fi);
        }
      }
      unsigned ov[8];
      #pragma unroll
      for (int e = 0; e < 8; ++e) {
        unsigned xs = (ux[e >> 1] >> ((e & 1) * 16)) & 0xffffu;
        ov[e] = xs | ((unsigned)f2b(rel[e]) << 16);        // (x_c, rel_c) interleave
      }
      uint4 o0; o0.x = ov[0]; o0.y = ov[1]; o0.z = ov[2]; o0.w = ov[3];
      uint4 o1; o1.x = ov[4]; o1.y = ov[5]; o1.z = ov[6]; o1.w = ov[7];
      *(uint4*)&m_lds[nl][lane * 16] = o0;
      *(uint4*)&m_lds[nl][lane * 16 + 8] = o1;
    }
  }
  __syncthreads();

  // -------- phase 2: grouped GEMM via MFMA --------
  // wave wv -> group g = wv>>1, cout half = wv&1: owns 96 rows x 32 cols
  int g    = wv >> 1;
  int half = wv & 1;
  int rb   = g * 192 + half * 96;    // cout base
  int l15  = lane & 15;
  int lhi  = lane >> 4;

  f32x4 acc[6][2];
  #pragma unroll
  for (int rt = 0; rt < 6; ++rt)
    #pragma unroll
    for (int ct = 0; ct < 2; ++ct)
      acc[rt][ct] = (f32x4){0.f, 0.f, 0.f, 0.f};

  #pragma unroll
  for (int ks = 0; ks < 6; ++ks) {           // K = 192 = 6 x 32
    int k0 = ks * 32 + lhi * 8;
    bf16x8 bfrag[2];
    #pragma unroll
    for (int ct = 0; ct < 2; ++ct) {
      int n = ct * 16 + l15;
      bfrag[ct] = *(const bf16x8*)&m_lds[n][g * FANIN_ + k0];   // B[k][n]
    }
    #pragma unroll
    for (int rt = 0; rt < 6; ++rt) {
      int co = rb + rt * 16 + l15;
      bf16x8 afrag = *(const bf16x8*)(Wb + (size_t)co * FANIN_ + k0);  // A[m][k]
      #pragma unroll
      for (int ct = 0; ct < 2; ++ct)
        acc[rt][ct] = __builtin_amdgcn_mfma_f32_16x16x32_bf16(afrag, bfrag[ct],
                                                              acc[rt][ct], 0, 0, 0);
    }
  }

  // -------- epilogue: bias + ReLU, store --------
  float* outb = out + (size_t)b * C_OUT_ * N_;
  #pragma unroll
  for (int rt = 0; rt < 6; ++rt) {
    int co_b = rb + rt * 16 + lhi * 4;       // D row = (lane>>4)*4 + reg (m89-verified)
    #pragma unroll
    for (int ct = 0; ct < 2; ++ct) {
      int n = n0 + ct * 16 + l15;            // D col = lane&15
      #pragma unroll
      for (int r = 0; r < 4; ++r) {
        int co = co_b + r;
        float v = acc[rt][ct][r] + bias[co];
        outb[(size_t)co * N_ + n] = v > 0.f ? v : 0.f;
      }
    }
  }
}

extern "C" void kernel_launch(void* const* d_in, const int* in_sizes, int n_in,
                              void* d_out, int out_size, void* d_ws, size_t ws_size,
                              hipStream_t stream) {
  const float* x    = (const float*)d_in[0];
  const int*   eidx = (const int*)d_in[1];
  const float* W    = (const float*)d_in[2];
  const float* bias = (const float*)d_in[3];
  float* out = (float*)d_out;

  unsigned short* xt = (unsigned short*)d_ws;                 // B*N*C_IN bf16 = 25.2 MB
  unsigned short* Wb = xt + (size_t)B_ * N_ * C_IN_;          // C_OUT*FANIN bf16 = 0.3 MB

  wconv_kernel<<<(C_OUT_ * FANIN_ + 255) / 256, 256, 0, stream>>>(W, Wb);

  dim3 tg(N_ / 32, C_IN_ / 64, B_);
  transpose_kernel<<<tg, 256, 0, stream>>>(x, xt);

  dim3 mg(N_ / NT, B_);
  mrconv_kernel<<<mg, 512, 0, stream>>>(xt, eidx, Wb, bias, out);
}

// Round 2
// 127.465 us; speedup vs baseline: 1.0951x; 1.0951x over previous
//
#include <hip/hip_runtime.h>
#include <hip/hip_bf16.h>

#define B_ 4
#define C_IN_ 384
#define C_OUT_ 768
#define N_ 8192
#define K_ 16
#define FANIN_ 192     // 2*C_IN/GROUPS
#define NT 32          // n-columns per block
#define PADC (2*C_IN_ + 8)   // 776: pad 8 bf16 to break 1536B-stride bank conflicts

typedef float f32x4 __attribute__((ext_vector_type(4)));
typedef short bf16x8 __attribute__((ext_vector_type(8)));

__device__ __forceinline__ unsigned short f2b(float f) {
  union { float f; unsigned u; } v; v.f = f;
  unsigned r = v.u + 0x7FFFu + ((v.u >> 16) & 1u);  // RNE
  return (unsigned short)(r >> 16);
}
__device__ __forceinline__ float hi_f(unsigned u) {  // bf16 in high 16 bits -> f32
  union { unsigned u; float f; } v; v.u = u & 0xffff0000u; return v.f;
}
__device__ __forceinline__ float lo_f(unsigned u) {  // bf16 in low 16 bits -> f32
  union { unsigned u; float f; } v; v.u = u << 16; return v.f;
}

// ---- kernel 1: W fp32 -> bf16 ----
__global__ __launch_bounds__(256) void wconv_kernel(const float* __restrict__ W,
                                                    unsigned short* __restrict__ Wb) {
  int i = blockIdx.x * 256 + threadIdx.x;
  if (i < C_OUT_ * FANIN_) Wb[i] = f2b(W[i]);
}

// ---- kernel 2: transpose x [B][C][N] f32 -> xt [B][N][C] bf16 ----
__global__ __launch_bounds__(256) void transpose_kernel(const float* __restrict__ x,
                                                        unsigned short* __restrict__ xt) {
  __shared__ float tile[32][65];
  int n0 = blockIdx.x * 32;
  int c0 = blockIdx.y * 64;
  int b  = blockIdx.z;
  int tx = threadIdx.x & 31;   // n offset
  int ty = threadIdx.x >> 5;   // 0..7
  const float* xp = x + (size_t)b * C_IN_ * N_;
  #pragma unroll
  for (int r = 0; r < 8; ++r) {
    int c = c0 + r * 8 + ty;
    tile[tx][r * 8 + ty] = xp[(size_t)c * N_ + n0 + tx];   // coalesced along n
  }
  __syncthreads();
  unsigned short* outp = xt + ((size_t)b * N_ + n0) * C_IN_ + c0;
  int cp = threadIdx.x & 31;   // channel pair
  int ny = threadIdx.x >> 5;
  #pragma unroll
  for (int p = 0; p < 4; ++p) {
    int nl = ny + p * 8;
    unsigned pk = (unsigned)f2b(tile[nl][cp * 2]) |
                  ((unsigned)f2b(tile[nl][cp * 2 + 1]) << 16);
    *(unsigned*)(outp + (size_t)nl * C_IN_ + cp * 2) = pk;  // coalesced along c
  }
}

// ---- kernel 3: fused gather+max -> LDS merged tile -> grouped MFMA GEMM ----
__global__ __launch_bounds__(512) void mrconv_kernel(
    const unsigned short* __restrict__ xt,   // [B][N][C_IN] bf16
    const int* __restrict__ eidx,            // [2][B][N][K]
    const unsigned short* __restrict__ Wb,   // [C_OUT][FANIN] bf16
    const float* __restrict__ bias,          // [C_OUT]
    float* __restrict__ out)                 // [B][C_OUT][N]
{
  __shared__ unsigned short m_lds[NT][PADC];  // merged: interleaved (x_c, rel_c)
  int tile = blockIdx.x;
  int b    = blockIdx.y;
  int n0   = tile * NT;
  int tid  = threadIdx.x;
  int wv   = tid >> 6;
  int lane = tid & 63;

  const unsigned short* xtb = xt + (size_t)b * N_ * C_IN_;
  const int* e0p = eidx + ((size_t)b * N_) * K_;          // edge_index[0][b]
  const int* e1p = eidx + ((size_t)(B_ + b) * N_) * K_;   // edge_index[1][b]

  // -------- phase 1: gather + max-relative, write merged tile to LDS --------
  // All 64 lanes: 6 channels/lane (64*6 = 384). All addressing scalar:
  // column index and gathered node ids forced to SGPR -> s_load indices,
  // SGPR-base + constant-voffset global loads.
  int cbase = lane * 6;                                    // channel base
  for (int s = 0; s < 4; ++s) {
    int nl = wv * 4 + s;                                   // 8 waves x 4 cols = 32
    int nb = __builtin_amdgcn_readfirstlane(n0 + nl);
    const int* e0 = e0p + (size_t)nb * K_;
    const int* e1 = e1p + (size_t)nb * K_;
    uint3 xv = *(const uint3*)(xtb + (size_t)nb * C_IN_ + cbase);   // self (6 ch)

    float rel[6];
    #pragma unroll
    for (int c = 0; c < 6; ++c) rel[c] = -1e30f;

    #pragma unroll 4
    for (int k = 0; k < K_; ++k) {
      int j = __builtin_amdgcn_readfirstlane(e0[k]);
      int i = __builtin_amdgcn_readfirstlane(e1[k]);
      uint3 vj = *(const uint3*)(xtb + (size_t)j * C_IN_ + cbase);
      uint3 vi = *(const uint3*)(xtb + (size_t)i * C_IN_ + cbase);
      unsigned uj[3] = {vj.x, vj.y, vj.z};
      unsigned ui[3] = {vi.x, vi.y, vi.z};
      #pragma unroll
      for (int d = 0; d < 3; ++d) {
        rel[2*d]   = fmaxf(rel[2*d],   lo_f(uj[d]) - lo_f(ui[d]));
        rel[2*d+1] = fmaxf(rel[2*d+1], hi_f(uj[d]) - hi_f(ui[d]));
      }
    }

    // pack interleaved (x_c, rel_c): dword c = x_c | rel_c<<16
    unsigned xd[3] = {xv.x, xv.y, xv.z};
    unsigned od[6];
    #pragma unroll
    for (int c = 0; c < 6; ++c) {
      union { float f; unsigned u; } r; r.f = rel[c];
      unsigned rh = (r.u + 0x7fffu + ((r.u >> 16) & 1u)) & 0xffff0000u;  // RNE, high half
      unsigned xs = (c & 1) ? (xd[c >> 1] >> 16) : (xd[c >> 1] & 0xffffu);
      od[c] = xs | rh;
    }
    uint2* dst = (uint2*)&m_lds[nl][12 * lane];
    dst[0] = (uint2){od[0], od[1]};
    dst[1] = (uint2){od[2], od[3]};
    dst[2] = (uint2){od[4], od[5]};
  }
  __syncthreads();

  // -------- phase 2: grouped GEMM via MFMA --------
  // wave wv -> group g = wv>>1, cout half = wv&1: owns 96 rows x 32 cols
  int g    = wv >> 1;
  int half = wv & 1;
  int rb   = g * 192 + half * 96;    // cout base
  int l15  = lane & 15;
  int lhi  = lane >> 4;

  f32x4 acc[6][2];
  #pragma unroll
  for (int rt = 0; rt < 6; ++rt)
    #pragma unroll
    for (int ct = 0; ct < 2; ++ct)
      acc[rt][ct] = (f32x4){0.f, 0.f, 0.f, 0.f};

  #pragma unroll
  for (int ks = 0; ks < 6; ++ks) {           // K = 192 = 6 x 32
    int k0 = ks * 32 + lhi * 8;
    bf16x8 bfrag[2];
    #pragma unroll
    for (int ct = 0; ct < 2; ++ct) {
      int n = ct * 16 + l15;
      bfrag[ct] = *(const bf16x8*)&m_lds[n][g * FANIN_ + k0];   // B[k][n]
    }
    #pragma unroll
    for (int rt = 0; rt < 6; ++rt) {
      int co = rb + rt * 16 + l15;
      bf16x8 afrag = *(const bf16x8*)(Wb + (size_t)co * FANIN_ + k0);  // A[m][k]
      #pragma unroll
      for (int ct = 0; ct < 2; ++ct)
        acc[rt][ct] = __builtin_amdgcn_mfma_f32_16x16x32_bf16(afrag, bfrag[ct],
                                                              acc[rt][ct], 0, 0, 0);
    }
  }

  // -------- epilogue: bias + ReLU, store --------
  float* outb = out + (size_t)b * C_OUT_ * N_;
  #pragma unroll
  for (int rt = 0; rt < 6; ++rt) {
    int co_b = rb + rt * 16 + lhi * 4;       // D row = (lane>>4)*4 + reg (m89-verified)
    #pragma unroll
    for (int ct = 0; ct < 2; ++ct) {
      int n = n0 + ct * 16 + l15;            // D col = lane&15
      #pragma unroll
      for (int r = 0; r < 4; ++r) {
        int co = co_b + r;
        float v = acc[rt][ct][r] + bias[co];
        outb[(size_t)co * N_ + n] = v > 0.f ? v : 0.f;
      }
    }
  }
}

extern "C" void kernel_launch(void* const* d_in, const int* in_sizes, int n_in,
                              void* d_out, int out_size, void* d_ws, size_t ws_size,
                              hipStream_t stream) {
  const float* x    = (const float*)d_in[0];
  const int*   eidx = (const int*)d_in[1];
  const float* W    = (const float*)d_in[2];
  const float* bias = (const float*)d_in[3];
  float* out = (float*)d_out;

  unsigned short* xt = (unsigned short*)d_ws;                 // B*N*C_IN bf16 = 25.2 MB
  unsigned short* Wb = xt + (size_t)B_ * N_ * C_IN_;          // C_OUT*FANIN bf16 = 0.3 MB

  wconv_kernel<<<(C_OUT_ * FANIN_ + 255) / 256, 256, 0, stream>>>(W, Wb);

  dim3 tg(N_ / 32, C_IN_ / 64, B_);
  transpose_kernel<<<tg, 256, 0, stream>>>(x, xt);

  dim3 mg(N_ / NT, B_);
  mrconv_kernel<<<mg, 512, 0, stream>>>(xt, eidx, Wb, bias, out);
}